// Round 1
// baseline (529.052 us; speedup 1.0000x reference)
//
#include <hip/hip_runtime.h>

// ParticleKernel: B=4, N=2048, D=512, P=16, K=4
// K1: projm_t[c][b*N+j] = bf16( mass[b,j] * sum_in charge[b,j,in]*W_charge[c,in] )   (c = k*D+d, 2048x8192)
// K2: field[b*N+i][c]   = bf16( sum_j exp(-dist2(b,i,j)/(2*bw_k+eps)) * projm_t[c][b*N+j] ),  k = c/512
// K3: out[b*N+i][dout]  = sum_c field[b*N+i][c] * W_combine[dout][c]   (fp32, into d_out)
// K4: LayerNorm rows of d_out in place.

typedef __bf16 bf16x8 __attribute__((ext_vector_type(8)));
typedef float f32x4 __attribute__((ext_vector_type(4)));

__device__ __forceinline__ unsigned short f2bf(float f) {
    // round-to-nearest-even fp32 -> bf16 (finite inputs only)
    unsigned u = __float_as_uint(f);
    unsigned r = (u + 0x7fffu + ((u >> 16) & 1u)) >> 16;
    return (unsigned short)r;
}

// ---------------- K1: projection GEMM (gemm_bt), output transposed + mass scale ----------------
// C[m=c][n=b*N+j] = sum_k Wc[m][k] * charge[n][k];  M=2048, N=8192, K=512
__global__ __launch_bounds__(256, 2) void k1_proj(const float* __restrict__ Wc,      // [2048][512]
                                                  const float* __restrict__ charge,  // [8192][512]
                                                  const float* __restrict__ mass,    // [8192]
                                                  unsigned short* __restrict__ projm_t) // [2048][8192] bf16
{
    __shared__ alignas(16) unsigned short As[128 * 40];
    __shared__ alignas(16) unsigned short Bs[128 * 40];
    const int tid = threadIdx.x;
    const int lane = tid & 63, wid = tid >> 6;
    const int q = lane >> 4, l15 = lane & 15;
    const int m0 = blockIdx.y * 128, n0 = blockIdx.x * 128;
    const int wm = (wid & 1) * 64, wn = (wid >> 1) * 64;

    f32x4 acc[4][4];
#pragma unroll
    for (int i = 0; i < 4; i++)
#pragma unroll
        for (int j = 0; j < 4; j++) acc[i][j] = (f32x4){0.f, 0.f, 0.f, 0.f};

    const int rr = tid >> 3, ch = tid & 7;  // rr 0..31, ch 0..7 (float4 chunks of 32-wide K tile)
    for (int k0 = 0; k0 < 512; k0 += 32) {
        __syncthreads();
#pragma unroll
        for (int rep = 0; rep < 4; rep++) {
            int row = rr + rep * 32;
            float4 a = *reinterpret_cast<const float4*>(&Wc[(size_t)(m0 + row) * 512 + k0 + ch * 4]);
            float4 b = *reinterpret_cast<const float4*>(&charge[(size_t)(n0 + row) * 512 + k0 + ch * 4]);
            uint2 pa, pb;
            pa.x = (unsigned)f2bf(a.x) | ((unsigned)f2bf(a.y) << 16);
            pa.y = (unsigned)f2bf(a.z) | ((unsigned)f2bf(a.w) << 16);
            pb.x = (unsigned)f2bf(b.x) | ((unsigned)f2bf(b.y) << 16);
            pb.y = (unsigned)f2bf(b.z) | ((unsigned)f2bf(b.w) << 16);
            *reinterpret_cast<uint2*>(&As[row * 40 + ch * 4]) = pa;
            *reinterpret_cast<uint2*>(&Bs[row * 40 + ch * 4]) = pb;
        }
        __syncthreads();
        bf16x8 af[4], bfr[4];
#pragma unroll
        for (int it = 0; it < 4; it++)
            af[it] = *reinterpret_cast<const bf16x8*>(&As[(wm + it * 16 + l15) * 40 + q * 8]);
#pragma unroll
        for (int ct = 0; ct < 4; ct++)
            bfr[ct] = *reinterpret_cast<const bf16x8*>(&Bs[(wn + ct * 16 + l15) * 40 + q * 8]);
#pragma unroll
        for (int it = 0; it < 4; it++)
#pragma unroll
            for (int ct = 0; ct < 4; ct++)
                acc[it][ct] = __builtin_amdgcn_mfma_f32_16x16x32_bf16(af[it], bfr[ct], acc[it][ct], 0, 0, 0);
    }
    // epilogue: scale by mass[n], store bf16 transposed
#pragma unroll
    for (int ct = 0; ct < 4; ct++) {
        int n = n0 + wn + ct * 16 + l15;
        float mf = mass[n];
#pragma unroll
        for (int it = 0; it < 4; it++) {
            int mrow = m0 + wm + it * 16 + q * 4;
#pragma unroll
            for (int r = 0; r < 4; r++)
                projm_t[(size_t)(mrow + r) * 8192 + n] = f2bf(acc[it][ct][r] * mf);
        }
    }
}

// ---------------- K2: fused w-compute + field GEMM ----------------
// block: b = z, i-tile(64) = y, c-tile(256) = x (one bandwidth k per block since 256 | 512)
__global__ __launch_bounds__(256, 2) void k2_field(const float* __restrict__ pos,       // [4][2048][16]
                                                   const float* __restrict__ logbw,     // [4]
                                                   const unsigned short* __restrict__ projm_t, // [2048][8192]
                                                   unsigned short* __restrict__ field)  // [8192][2048] bf16
{
    __shared__ alignas(16) float pI[64 * 16];
    __shared__ alignas(16) float pJ[32 * 16];
    __shared__ alignas(16) unsigned short Wl[64 * 40];
    __shared__ alignas(16) unsigned short Bs[256 * 40];

    const int tid = threadIdx.x, lane = tid & 63, wid = tid >> 6;
    const int q = lane >> 4, l15 = lane & 15;
    const int b = blockIdx.z, i0 = blockIdx.y * 64, c0 = blockIdx.x * 256;
    const int kb = c0 / 512;
    const float bw = __expf(logbw[kb]);
    const float s2 = -1.4426950408889634f / (2.0f * bw + 1e-8f);  // w = exp2(dist2 * s2)

    {   // stage pI once: 64 rows x 16 floats
        int row = tid >> 2, chp = tid & 3;
        *reinterpret_cast<float4*>(&pI[row * 16 + chp * 4]) =
            *reinterpret_cast<const float4*>(&pos[(size_t)((b * 2048 + i0 + row) * 16) + chp * 4]);
    }

    f32x4 acc[4][4];
#pragma unroll
    for (int i = 0; i < 4; i++)
#pragma unroll
        for (int j = 0; j < 4; j++) acc[i][j] = (f32x4){0.f, 0.f, 0.f, 0.f};

    const int jt = tid & 31, ibase = (tid >> 5) * 8;  // phase-1 mapping: fixed j, 8 i's per thread

    for (int j0 = 0; j0 < 2048; j0 += 32) {
        __syncthreads();
        if (tid < 128) {  // stage pJ: 32 rows x 16 floats
            int row = tid >> 2, chp = tid & 3;
            *reinterpret_cast<float4*>(&pJ[row * 16 + chp * 4]) =
                *reinterpret_cast<const float4*>(&pos[(size_t)((b * 2048 + j0 + row) * 16) + chp * 4]);
        }
        {   // stage Bs: row c = tid, 32 bf16 (64B) per row
            const unsigned short* src = &projm_t[(size_t)(c0 + tid) * 8192 + b * 2048 + j0];
#pragma unroll
            for (int chb = 0; chb < 4; chb++)
                *reinterpret_cast<int4*>(&Bs[tid * 40 + chb * 8]) =
                    *reinterpret_cast<const int4*>(&src[chb * 8]);
        }
        __syncthreads();
        {   // phase 1: w[64i][32j] in fp32, store bf16
            float pj[16];
#pragma unroll
            for (int d = 0; d < 16; d++) pj[d] = pJ[jt * 16 + d];
#pragma unroll
            for (int ii = 0; ii < 8; ii++) {
                float ds = 0.f;
#pragma unroll
                for (int d = 0; d < 16; d++) {
                    float df = pI[(ibase + ii) * 16 + d] - pj[d];
                    ds = __builtin_fmaf(df, df, ds);
                }
                Wl[(ibase + ii) * 40 + jt] = f2bf(exp2f(ds * s2));
            }
        }
        __syncthreads();
        // phase 2: MFMA  (A = w tile [i][j], B = projm_t tile [c][j])
        bf16x8 af[4], bfr[4];
#pragma unroll
        for (int it = 0; it < 4; it++)
            af[it] = *reinterpret_cast<const bf16x8*>(&Wl[(it * 16 + l15) * 40 + q * 8]);
#pragma unroll
        for (int ct = 0; ct < 4; ct++)
            bfr[ct] = *reinterpret_cast<const bf16x8*>(&Bs[(wid * 64 + ct * 16 + l15) * 40 + q * 8]);
#pragma unroll
        for (int it = 0; it < 4; it++)
#pragma unroll
            for (int ct = 0; ct < 4; ct++)
                acc[it][ct] = __builtin_amdgcn_mfma_f32_16x16x32_bf16(af[it], bfr[ct], acc[it][ct], 0, 0, 0);
    }
    // epilogue: store field bf16 row-major [b*N+i][c]
#pragma unroll
    for (int it = 0; it < 4; it++) {
#pragma unroll
        for (int ct = 0; ct < 4; ct++) {
            int gi = b * 2048 + i0 + it * 16 + q * 4;
            int gc = c0 + wid * 64 + ct * 16 + l15;
#pragma unroll
            for (int r = 0; r < 4; r++)
                field[(size_t)(gi + r) * 2048 + gc] = f2bf(acc[it][ct][r]);
        }
    }
}

// ---------------- K3: combine GEMM (gemm_bt), fp32 out into d_out ----------------
// C[m=b*N+i][n=dout] = sum_c field[m][c] * Wcb[n][c];  M=8192, N=512, K=2048
__global__ __launch_bounds__(256, 2) void k3_combine(const unsigned short* __restrict__ field, // [8192][2048] bf16
                                                     const float* __restrict__ Wcb,            // [512][2048]
                                                     float* __restrict__ out)                  // [8192][512]
{
    __shared__ alignas(16) unsigned short As[128 * 40];
    __shared__ alignas(16) unsigned short Bs[128 * 40];
    const int tid = threadIdx.x;
    const int lane = tid & 63, wid = tid >> 6;
    const int q = lane >> 4, l15 = lane & 15;
    const int m0 = blockIdx.y * 128, n0 = blockIdx.x * 128;
    const int wm = (wid & 1) * 64, wn = (wid >> 1) * 64;

    f32x4 acc[4][4];
#pragma unroll
    for (int i = 0; i < 4; i++)
#pragma unroll
        for (int j = 0; j < 4; j++) acc[i][j] = (f32x4){0.f, 0.f, 0.f, 0.f};

    for (int k0 = 0; k0 < 2048; k0 += 32) {
        __syncthreads();
        {   // A: bf16 source, 128 rows x 32 bf16 (64B/row) — straight 16B copies
            int rowb = tid >> 2, chA = tid & 3;
#pragma unroll
            for (int rep = 0; rep < 2; rep++) {
                int row = rowb + rep * 64;
                int4 v = *reinterpret_cast<const int4*>(&field[(size_t)(m0 + row) * 2048 + k0 + chA * 8]);
                *reinterpret_cast<int4*>(&As[row * 40 + chA * 8]) = v;
            }
        }
        {   // B: fp32 source, cvt
            int rr = tid >> 3, ch = tid & 7;
#pragma unroll
            for (int rep = 0; rep < 4; rep++) {
                int row = rr + rep * 32;
                float4 bv = *reinterpret_cast<const float4*>(&Wcb[(size_t)(n0 + row) * 2048 + k0 + ch * 4]);
                uint2 pb;
                pb.x = (unsigned)f2bf(bv.x) | ((unsigned)f2bf(bv.y) << 16);
                pb.y = (unsigned)f2bf(bv.z) | ((unsigned)f2bf(bv.w) << 16);
                *reinterpret_cast<uint2*>(&Bs[row * 40 + ch * 4]) = pb;
            }
        }
        __syncthreads();
        bf16x8 af[4], bfr[4];
#pragma unroll
        for (int it = 0; it < 4; it++)
            af[it] = *reinterpret_cast<const bf16x8*>(&As[(wm + it * 16 + l15) * 40 + q * 8]);
#pragma unroll
        for (int ct = 0; ct < 4; ct++)
            bfr[ct] = *reinterpret_cast<const bf16x8*>(&Bs[(wn + ct * 16 + l15) * 40 + q * 8]);
#pragma unroll
        for (int it = 0; it < 4; it++)
#pragma unroll
            for (int ct = 0; ct < 4; ct++)
                acc[it][ct] = __builtin_amdgcn_mfma_f32_16x16x32_bf16(af[it], bfr[ct], acc[it][ct], 0, 0, 0);
    }
#pragma unroll
    for (int it = 0; it < 4; it++) {
#pragma unroll
        for (int ct = 0; ct < 4; ct++) {
            int m = m0 + wm + it * 16 + q * 4;
            int n = n0 + wn + ct * 16 + l15;
#pragma unroll
            for (int r = 0; r < 4; r++)
                out[(size_t)(m + r) * 512 + n] = acc[it][ct][r];
        }
    }
}

// ---------------- K4: LayerNorm rows of d_out in place ----------------
__global__ __launch_bounds__(256) void k4_ln(float* __restrict__ out,
                                             const float* __restrict__ gamma,
                                             const float* __restrict__ beta)
{
    __shared__ float red[8];
    const int row = blockIdx.x, tid = threadIdx.x;
    float2 x = *reinterpret_cast<const float2*>(&out[(size_t)row * 512 + tid * 2]);
    float s = x.x + x.y;
    float ss = x.x * x.x + x.y * x.y;
#pragma unroll
    for (int off = 32; off > 0; off >>= 1) {
        s += __shfl_down(s, off);
        ss += __shfl_down(ss, off);
    }
    int wid = tid >> 6;
    if ((tid & 63) == 0) { red[wid * 2] = s; red[wid * 2 + 1] = ss; }
    __syncthreads();
    s = red[0] + red[2] + red[4] + red[6];
    ss = red[1] + red[3] + red[5] + red[7];
    float mean = s * (1.f / 512.f);
    float var = ss * (1.f / 512.f) - mean * mean;
    float inv = rsqrtf(var + 1e-5f);
    float g0 = gamma[tid * 2], g1 = gamma[tid * 2 + 1];
    float b0 = beta[tid * 2], b1 = beta[tid * 2 + 1];
    float2 o;
    o.x = (x.x - mean) * inv * g0 + b0;
    o.y = (x.y - mean) * inv * g1 + b1;
    *reinterpret_cast<float2*>(&out[(size_t)row * 512 + tid * 2]) = o;
}

extern "C" void kernel_launch(void* const* d_in, const int* in_sizes, int n_in,
                              void* d_out, int out_size, void* d_ws, size_t ws_size,
                              hipStream_t stream)
{
    const float* charge   = (const float*)d_in[0];
    const float* position = (const float*)d_in[1];
    const float* mass     = (const float*)d_in[2];
    const float* logbw    = (const float*)d_in[3];
    const float* Wc       = (const float*)d_in[4];
    const float* Wcb      = (const float*)d_in[5];
    const float* gamma    = (const float*)d_in[6];
    const float* beta     = (const float*)d_in[7];

    unsigned short* projm_t = (unsigned short*)d_ws;                 // 2048*8192 bf16 = 32 MB
    unsigned short* field   = projm_t + (size_t)2048 * 8192;         // 8192*2048 bf16 = 32 MB
    float* out = (float*)d_out;

    dim3 g1(64, 16);
    k1_proj<<<g1, 256, 0, stream>>>(Wc, charge, mass, projm_t);
    dim3 g2(8, 32, 4);
    k2_field<<<g2, 256, 0, stream>>>(position, logbw, projm_t, field);
    dim3 g3(4, 64);
    k3_combine<<<g3, 256, 0, stream>>>(field, Wcb, out);
    k4_ln<<<8192, 256, 0, stream>>>(out, gamma, beta);
}

// Round 2
// 490.286 us; speedup vs baseline: 1.0791x; 1.0791x over previous
//
#include <hip/hip_runtime.h>

// ParticleKernel: B=4, N=2048, D=512, P=16, K=4
// K1: projm_t[c][b*N+j] = bf16( mass[b,j] * sum_in charge[b,j,in]*W_charge[c,in] )   (c = k*D+d, 2048x8192)
// K2: field[b*N+i][c]   = bf16( sum_j exp(-dist2(b,i,j)/(2*bw_k+eps)) * projm_t[c][b*N+j] ),  k = c/512
//     dist2 via MFMA Gram: dist2 = ri + rj - 2*(hi_i.hi_j + hi_i.lo_j + lo_i.hi_j)  (bf16 hi/lo split)
// K3: out[b*N+i][dout]  = sum_c field[b*N+i][c] * W_combine[dout][c]   (fp32, into d_out)
// K4: LayerNorm rows of d_out in place.

typedef __bf16 bf16x8 __attribute__((ext_vector_type(8)));
typedef float f32x4 __attribute__((ext_vector_type(4)));

__device__ __forceinline__ unsigned short f2bf(float f) {
    unsigned u = __float_as_uint(f);
    unsigned r = (u + 0x7fffu + ((u >> 16) & 1u)) >> 16;
    return (unsigned short)r;
}
__device__ __forceinline__ float bf2f(unsigned short h) {
    return __uint_as_float(((unsigned)h) << 16);
}

// ---------------- K1: projection GEMM (gemm_bt), output transposed + mass scale ----------------
__global__ __launch_bounds__(256, 2) void k1_proj(const float* __restrict__ Wc,      // [2048][512]
                                                  const float* __restrict__ charge,  // [8192][512]
                                                  const float* __restrict__ mass,    // [8192]
                                                  unsigned short* __restrict__ projm_t) // [2048][8192] bf16
{
    __shared__ alignas(16) unsigned short As[128 * 40];
    __shared__ alignas(16) unsigned short Bs[128 * 40];
    const int tid = threadIdx.x;
    const int lane = tid & 63, wid = tid >> 6;
    const int q = lane >> 4, l15 = lane & 15;
    const int m0 = blockIdx.y * 128, n0 = blockIdx.x * 128;
    const int wm = (wid & 1) * 64, wn = (wid >> 1) * 64;

    f32x4 acc[4][4];
#pragma unroll
    for (int i = 0; i < 4; i++)
#pragma unroll
        for (int j = 0; j < 4; j++) acc[i][j] = (f32x4){0.f, 0.f, 0.f, 0.f};

    const int rr = tid >> 3, ch = tid & 7;
    for (int k0 = 0; k0 < 512; k0 += 32) {
        __syncthreads();
#pragma unroll
        for (int rep = 0; rep < 4; rep++) {
            int row = rr + rep * 32;
            float4 a = *reinterpret_cast<const float4*>(&Wc[(size_t)(m0 + row) * 512 + k0 + ch * 4]);
            float4 b = *reinterpret_cast<const float4*>(&charge[(size_t)(n0 + row) * 512 + k0 + ch * 4]);
            uint2 pa, pb;
            pa.x = (unsigned)f2bf(a.x) | ((unsigned)f2bf(a.y) << 16);
            pa.y = (unsigned)f2bf(a.z) | ((unsigned)f2bf(a.w) << 16);
            pb.x = (unsigned)f2bf(b.x) | ((unsigned)f2bf(b.y) << 16);
            pb.y = (unsigned)f2bf(b.z) | ((unsigned)f2bf(b.w) << 16);
            *reinterpret_cast<uint2*>(&As[row * 40 + ch * 4]) = pa;
            *reinterpret_cast<uint2*>(&Bs[row * 40 + ch * 4]) = pb;
        }
        __syncthreads();
        bf16x8 af[4], bfr[4];
#pragma unroll
        for (int it = 0; it < 4; it++)
            af[it] = *reinterpret_cast<const bf16x8*>(&As[(wm + it * 16 + l15) * 40 + q * 8]);
#pragma unroll
        for (int ct = 0; ct < 4; ct++)
            bfr[ct] = *reinterpret_cast<const bf16x8*>(&Bs[(wn + ct * 16 + l15) * 40 + q * 8]);
#pragma unroll
        for (int it = 0; it < 4; it++)
#pragma unroll
            for (int ct = 0; ct < 4; ct++)
                acc[it][ct] = __builtin_amdgcn_mfma_f32_16x16x32_bf16(af[it], bfr[ct], acc[it][ct], 0, 0, 0);
    }
#pragma unroll
    for (int ct = 0; ct < 4; ct++) {
        int n = n0 + wn + ct * 16 + l15;
        float mf = mass[n];
#pragma unroll
        for (int it = 0; it < 4; it++) {
            int mrow = m0 + wm + it * 16 + q * 4;
#pragma unroll
            for (int r = 0; r < 4; r++)
                projm_t[(size_t)(mrow + r) * 8192 + n] = f2bf(acc[it][ct][r] * mf);
        }
    }
}

// ---------------- K2: fused w-compute (MFMA Gram) + field GEMM ----------------
__global__ __launch_bounds__(256, 2) void k2_field(const float* __restrict__ pos,       // [4][2048][16]
                                                   const float* __restrict__ logbw,     // [4]
                                                   const unsigned short* __restrict__ projm_t, // [2048][8192]
                                                   unsigned short* __restrict__ field)  // [8192][2048] bf16
{
    __shared__ alignas(16) unsigned short pIhl[64 * 40];  // [i][hi(16)|lo(16)] + pad
    __shared__ alignas(16) unsigned short pjB1[32 * 40];  // [j][hi|hi]
    __shared__ alignas(16) unsigned short pjB2[32 * 40];  // [j][lo|0]
    __shared__ alignas(16) unsigned short Wl[64 * 40];    // w bf16 [i][j]
    __shared__ alignas(16) unsigned short Bs[256 * 40];   // projm_t tile [c][j]
    __shared__ float riS[64];
    __shared__ float rjS[32];

    const int tid = threadIdx.x, lane = tid & 63, wid = tid >> 6;
    const int q = lane >> 4, l15 = lane & 15;
    const int b = blockIdx.z, i0 = blockIdx.y * 64, c0 = blockIdx.x * 256;
    const int kb = c0 / 512;
    const float bw = __expf(logbw[kb]);
    const float s2 = -1.4426950408889634f / (2.0f * bw + 1e-8f);  // w = exp2(dist2 * s2)
    const float c2 = -2.0f * s2;

    // ---- per-block init: pIhl (hi|lo), riS, pjB2 upper zeros ----
    if (tid < 64) {
        const float* src = &pos[(size_t)((b * 2048 + i0 + tid) * 16)];
        float p[16];
#pragma unroll
        for (int cc = 0; cc < 4; cc++) {
            float4 v = *reinterpret_cast<const float4*>(&src[cc * 4]);
            p[cc * 4 + 0] = v.x; p[cc * 4 + 1] = v.y; p[cc * 4 + 2] = v.z; p[cc * 4 + 3] = v.w;
        }
        float ri = 0.f;
        unsigned short h[16], lo[16];
#pragma unroll
        for (int d = 0; d < 16; d++) {
            ri = __builtin_fmaf(p[d], p[d], ri);
            h[d] = f2bf(p[d]);
            lo[d] = f2bf(p[d] - bf2f(h[d]));
        }
        riS[tid] = ri;
        *reinterpret_cast<int4*>(&pIhl[tid * 40 + 0])  = *reinterpret_cast<int4*>(&h[0]);
        *reinterpret_cast<int4*>(&pIhl[tid * 40 + 8])  = *reinterpret_cast<int4*>(&h[8]);
        *reinterpret_cast<int4*>(&pIhl[tid * 40 + 16]) = *reinterpret_cast<int4*>(&lo[0]);
        *reinterpret_cast<int4*>(&pIhl[tid * 40 + 24]) = *reinterpret_cast<int4*>(&lo[8]);
    } else if (tid >= 128 && tid < 160) {
        int t = tid - 128;
        int4 z = {0, 0, 0, 0};
        *reinterpret_cast<int4*>(&pjB2[t * 40 + 16]) = z;
        *reinterpret_cast<int4*>(&pjB2[t * 40 + 24]) = z;
    }
    __syncthreads();

    // Gram A-frag: loop-invariant. wave wid handles i-tile wid. A[m=l15][k=q*8..]
    const bf16x8 afG = *reinterpret_cast<const bf16x8*>(&pIhl[(wid * 16 + l15) * 40 + q * 8]);

    f32x4 acc[4][4];
#pragma unroll
    for (int i = 0; i < 4; i++)
#pragma unroll
        for (int j = 0; j < 4; j++) acc[i][j] = (f32x4){0.f, 0.f, 0.f, 0.f};

    for (int j0 = 0; j0 < 2048; j0 += 32) {
        __syncthreads();
        // ---- stage pj hi/lo + rj (threads 0..31), Bs (all threads) ----
        if (tid < 32) {
            const float* src = &pos[(size_t)((b * 2048 + j0 + tid) * 16)];
            float p[16];
#pragma unroll
            for (int cc = 0; cc < 4; cc++) {
                float4 v = *reinterpret_cast<const float4*>(&src[cc * 4]);
                p[cc * 4 + 0] = v.x; p[cc * 4 + 1] = v.y; p[cc * 4 + 2] = v.z; p[cc * 4 + 3] = v.w;
            }
            float rj = 0.f;
            unsigned short h[16], lo[16];
#pragma unroll
            for (int d = 0; d < 16; d++) {
                rj = __builtin_fmaf(p[d], p[d], rj);
                h[d] = f2bf(p[d]);
                lo[d] = f2bf(p[d] - bf2f(h[d]));
            }
            rjS[tid] = rj;
            *reinterpret_cast<int4*>(&pjB1[tid * 40 + 0])  = *reinterpret_cast<int4*>(&h[0]);
            *reinterpret_cast<int4*>(&pjB1[tid * 40 + 8])  = *reinterpret_cast<int4*>(&h[8]);
            *reinterpret_cast<int4*>(&pjB1[tid * 40 + 16]) = *reinterpret_cast<int4*>(&h[0]);
            *reinterpret_cast<int4*>(&pjB1[tid * 40 + 24]) = *reinterpret_cast<int4*>(&h[8]);
            *reinterpret_cast<int4*>(&pjB2[tid * 40 + 0])  = *reinterpret_cast<int4*>(&lo[0]);
            *reinterpret_cast<int4*>(&pjB2[tid * 40 + 8])  = *reinterpret_cast<int4*>(&lo[8]);
        }
        {   // Bs: row c = tid, 32 bf16 per row
            const unsigned short* src = &projm_t[(size_t)(c0 + tid) * 8192 + b * 2048 + j0];
#pragma unroll
            for (int chb = 0; chb < 4; chb++)
                *reinterpret_cast<int4*>(&Bs[tid * 40 + chb * 8]) =
                    *reinterpret_cast<const int4*>(&src[chb * 8]);
        }
        __syncthreads();
        // ---- Gram MFMAs: wave wid -> output tiles (it=wid, jt2=0,1) ----
#pragma unroll
        for (int jt2 = 0; jt2 < 2; jt2++) {
            bf16x8 b2 = *reinterpret_cast<const bf16x8*>(&pjB2[(jt2 * 16 + l15) * 40 + q * 8]);
            bf16x8 b1 = *reinterpret_cast<const bf16x8*>(&pjB1[(jt2 * 16 + l15) * 40 + q * 8]);
            f32x4 g = (f32x4){0.f, 0.f, 0.f, 0.f};
            g = __builtin_amdgcn_mfma_f32_16x16x32_bf16(afG, b2, g, 0, 0, 0);
            g = __builtin_amdgcn_mfma_f32_16x16x32_bf16(afG, b1, g, 0, 0, 0);
            // C layout: col(j) = l15, row(i) = q*4+r
            int j = jt2 * 16 + l15;
            float rj = rjS[j];
#pragma unroll
            for (int r = 0; r < 4; r++) {
                int i = wid * 16 + q * 4 + r;
                float x = __builtin_fmaf(g[r], c2, (riS[i] + rj) * s2);
                Wl[i * 40 + j] = f2bf(exp2f(x));
            }
        }
        __syncthreads();
        // ---- field MFMA: A = w tile [i][j], B = projm_t tile [c][j] ----
        bf16x8 af[4], bfr[4];
#pragma unroll
        for (int it = 0; it < 4; it++)
            af[it] = *reinterpret_cast<const bf16x8*>(&Wl[(it * 16 + l15) * 40 + q * 8]);
#pragma unroll
        for (int ct = 0; ct < 4; ct++)
            bfr[ct] = *reinterpret_cast<const bf16x8*>(&Bs[(wid * 64 + ct * 16 + l15) * 40 + q * 8]);
#pragma unroll
        for (int it = 0; it < 4; it++)
#pragma unroll
            for (int ct = 0; ct < 4; ct++)
                acc[it][ct] = __builtin_amdgcn_mfma_f32_16x16x32_bf16(af[it], bfr[ct], acc[it][ct], 0, 0, 0);
    }
#pragma unroll
    for (int it = 0; it < 4; it++) {
#pragma unroll
        for (int ct = 0; ct < 4; ct++) {
            int gi = b * 2048 + i0 + it * 16 + q * 4;
            int gc = c0 + wid * 64 + ct * 16 + l15;
#pragma unroll
            for (int r = 0; r < 4; r++)
                field[(size_t)(gi + r) * 2048 + gc] = f2bf(acc[it][ct][r]);
        }
    }
}

// ---------------- K3: combine GEMM (gemm_bt), fp32 out into d_out ----------------
__global__ __launch_bounds__(256, 2) void k3_combine(const unsigned short* __restrict__ field, // [8192][2048] bf16
                                                     const float* __restrict__ Wcb,            // [512][2048]
                                                     float* __restrict__ out)                  // [8192][512]
{
    __shared__ alignas(16) unsigned short As[128 * 40];
    __shared__ alignas(16) unsigned short Bs[128 * 40];
    const int tid = threadIdx.x;
    const int lane = tid & 63, wid = tid >> 6;
    const int q = lane >> 4, l15 = lane & 15;
    const int m0 = blockIdx.y * 128, n0 = blockIdx.x * 128;
    const int wm = (wid & 1) * 64, wn = (wid >> 1) * 64;

    f32x4 acc[4][4];
#pragma unroll
    for (int i = 0; i < 4; i++)
#pragma unroll
        for (int j = 0; j < 4; j++) acc[i][j] = (f32x4){0.f, 0.f, 0.f, 0.f};

    for (int k0 = 0; k0 < 2048; k0 += 32) {
        __syncthreads();
        {
            int rowb = tid >> 2, chA = tid & 3;
#pragma unroll
            for (int rep = 0; rep < 2; rep++) {
                int row = rowb + rep * 64;
                int4 v = *reinterpret_cast<const int4*>(&field[(size_t)(m0 + row) * 2048 + k0 + chA * 8]);
                *reinterpret_cast<int4*>(&As[row * 40 + chA * 8]) = v;
            }
        }
        {
            int rr = tid >> 3, ch = tid & 7;
#pragma unroll
            for (int rep = 0; rep < 4; rep++) {
                int row = rr + rep * 32;
                float4 bv = *reinterpret_cast<const float4*>(&Wcb[(size_t)(n0 + row) * 2048 + k0 + ch * 4]);
                uint2 pb;
                pb.x = (unsigned)f2bf(bv.x) | ((unsigned)f2bf(bv.y) << 16);
                pb.y = (unsigned)f2bf(bv.z) | ((unsigned)f2bf(bv.w) << 16);
                *reinterpret_cast<uint2*>(&Bs[row * 40 + ch * 4]) = pb;
            }
        }
        __syncthreads();
        bf16x8 af[4], bfr[4];
#pragma unroll
        for (int it = 0; it < 4; it++)
            af[it] = *reinterpret_cast<const bf16x8*>(&As[(wm + it * 16 + l15) * 40 + q * 8]);
#pragma unroll
        for (int ct = 0; ct < 4; ct++)
            bfr[ct] = *reinterpret_cast<const bf16x8*>(&Bs[(wn + ct * 16 + l15) * 40 + q * 8]);
#pragma unroll
        for (int it = 0; it < 4; it++)
#pragma unroll
            for (int ct = 0; ct < 4; ct++)
                acc[it][ct] = __builtin_amdgcn_mfma_f32_16x16x32_bf16(af[it], bfr[ct], acc[it][ct], 0, 0, 0);
    }
#pragma unroll
    for (int it = 0; it < 4; it++) {
#pragma unroll
        for (int ct = 0; ct < 4; ct++) {
            int m = m0 + wm + it * 16 + q * 4;
            int n = n0 + wn + ct * 16 + l15;
#pragma unroll
            for (int r = 0; r < 4; r++)
                out[(size_t)(m + r) * 512 + n] = acc[it][ct][r];
        }
    }
}

// ---------------- K4: LayerNorm rows of d_out in place ----------------
__global__ __launch_bounds__(256) void k4_ln(float* __restrict__ out,
                                             const float* __restrict__ gamma,
                                             const float* __restrict__ beta)
{
    __shared__ float red[8];
    const int row = blockIdx.x, tid = threadIdx.x;
    float2 x = *reinterpret_cast<const float2*>(&out[(size_t)row * 512 + tid * 2]);
    float s = x.x + x.y;
    float ss = x.x * x.x + x.y * x.y;
#pragma unroll
    for (int off = 32; off > 0; off >>= 1) {
        s += __shfl_down(s, off);
        ss += __shfl_down(ss, off);
    }
    int wid = tid >> 6;
    if ((tid & 63) == 0) { red[wid * 2] = s; red[wid * 2 + 1] = ss; }
    __syncthreads();
    s = red[0] + red[2] + red[4] + red[6];
    ss = red[1] + red[3] + red[5] + red[7];
    float mean = s * (1.f / 512.f);
    float var = ss * (1.f / 512.f) - mean * mean;
    float inv = rsqrtf(var + 1e-5f);
    float g0 = gamma[tid * 2], g1 = gamma[tid * 2 + 1];
    float b0 = beta[tid * 2], b1 = beta[tid * 2 + 1];
    float2 o;
    o.x = (x.x - mean) * inv * g0 + b0;
    o.y = (x.y - mean) * inv * g1 + b1;
    *reinterpret_cast<float2*>(&out[(size_t)row * 512 + tid * 2]) = o;
}

extern "C" void kernel_launch(void* const* d_in, const int* in_sizes, int n_in,
                              void* d_out, int out_size, void* d_ws, size_t ws_size,
                              hipStream_t stream)
{
    const float* charge   = (const float*)d_in[0];
    const float* position = (const float*)d_in[1];
    const float* mass     = (const float*)d_in[2];
    const float* logbw    = (const float*)d_in[3];
    const float* Wc       = (const float*)d_in[4];
    const float* Wcb      = (const float*)d_in[5];
    const float* gamma    = (const float*)d_in[6];
    const float* beta     = (const float*)d_in[7];

    unsigned short* projm_t = (unsigned short*)d_ws;                 // 2048*8192 bf16 = 32 MB
    unsigned short* field   = projm_t + (size_t)2048 * 8192;         // 8192*2048 bf16 = 32 MB
    float* out = (float*)d_out;

    dim3 g1(64, 16);
    k1_proj<<<g1, 256, 0, stream>>>(Wc, charge, mass, projm_t);
    dim3 g2(8, 32, 4);
    k2_field<<<g2, 256, 0, stream>>>(position, logbw, projm_t, field);
    dim3 g3(4, 64);
    k3_combine<<<g3, 256, 0, stream>>>(field, Wcb, out);
    k4_ln<<<8192, 256, 0, stream>>>(out, gamma, beta);
}

// Round 3
// 300.792 us; speedup vs baseline: 1.7589x; 1.6300x over previous
//
#include <hip/hip_runtime.h>

// ParticleKernel: B=4, N=2048, D=512, P=16, K=4
// K0p: pos -> hi/lo bf16 splits (posA=[hi|lo], posB1=[hi|hi], posB2=[lo|0]) + rsq=|p|^2   (in d_out scratch)
// K0c: fp32 -> bf16 bulk converts (charge, W_charge into field region; W_combine into projm_t region after K2)
// K1 : projm_t[c][b*N+j] = bf16( mass * charge @ Wc^T )  (m97-style, global_load_lds staging)
// K2 : field[b*N+i][c] = bf16( sum_j exp2(s2*dist2) * projm_t[c][j] ); dist2 via MFMA Gram hi/lo
// K3 : out = field @ Wcb^T (fp32 into d_out)
// K4 : LayerNorm in place.

typedef __bf16 bf16x8 __attribute__((ext_vector_type(8)));
typedef float f32x4 __attribute__((ext_vector_type(4)));

__device__ __forceinline__ unsigned short f2bf(float f) {
    unsigned u = __float_as_uint(f);
    unsigned r = (u + 0x7fffu + ((u >> 16) & 1u)) >> 16;
    return (unsigned short)r;
}
__device__ __forceinline__ float bf2f(unsigned short h) {
    return __uint_as_float(((unsigned)h) << 16);
}
__device__ __forceinline__ void g2l16(const unsigned short* g, unsigned short* l) {
    __builtin_amdgcn_global_load_lds(
        (const __attribute__((address_space(1))) unsigned int*)g,
        (__attribute__((address_space(3))) unsigned int*)l, 16, 0, 0);
}

// ---------------- K0p: position preprocess ----------------
__global__ __launch_bounds__(256) void k0_pos(const float* __restrict__ pos,
                                              unsigned short* __restrict__ posA,
                                              unsigned short* __restrict__ posB1,
                                              unsigned short* __restrict__ posB2,
                                              float* __restrict__ rsq)
{
    const int row = blockIdx.x * 256 + threadIdx.x;  // 0..8191
    const float* src = &pos[(size_t)row * 16];
    float p[16];
#pragma unroll
    for (int cc = 0; cc < 4; cc++) {
        float4 v = *reinterpret_cast<const float4*>(&src[cc * 4]);
        p[cc * 4 + 0] = v.x; p[cc * 4 + 1] = v.y; p[cc * 4 + 2] = v.z; p[cc * 4 + 3] = v.w;
    }
    float r = 0.f;
    unsigned short h[16], lo[16], z[8] = {0, 0, 0, 0, 0, 0, 0, 0};
#pragma unroll
    for (int d = 0; d < 16; d++) {
        r = __builtin_fmaf(p[d], p[d], r);
        h[d] = f2bf(p[d]);
        lo[d] = f2bf(p[d] - bf2f(h[d]));
    }
    rsq[row] = r;
    size_t o = (size_t)row * 32;
    *reinterpret_cast<int4*>(&posA[o + 0])   = *reinterpret_cast<int4*>(&h[0]);
    *reinterpret_cast<int4*>(&posA[o + 8])   = *reinterpret_cast<int4*>(&h[8]);
    *reinterpret_cast<int4*>(&posA[o + 16])  = *reinterpret_cast<int4*>(&lo[0]);
    *reinterpret_cast<int4*>(&posA[o + 24])  = *reinterpret_cast<int4*>(&lo[8]);
    *reinterpret_cast<int4*>(&posB1[o + 0])  = *reinterpret_cast<int4*>(&h[0]);
    *reinterpret_cast<int4*>(&posB1[o + 8])  = *reinterpret_cast<int4*>(&h[8]);
    *reinterpret_cast<int4*>(&posB1[o + 16]) = *reinterpret_cast<int4*>(&h[0]);
    *reinterpret_cast<int4*>(&posB1[o + 24]) = *reinterpret_cast<int4*>(&h[8]);
    *reinterpret_cast<int4*>(&posB2[o + 0])  = *reinterpret_cast<int4*>(&lo[0]);
    *reinterpret_cast<int4*>(&posB2[o + 8])  = *reinterpret_cast<int4*>(&lo[8]);
    *reinterpret_cast<int4*>(&posB2[o + 16]) = *reinterpret_cast<int4*>(&z[0]);
    *reinterpret_cast<int4*>(&posB2[o + 24]) = *reinterpret_cast<int4*>(&z[0]);
}

// ---------------- K0c: bulk fp32 -> bf16 convert (4 elems/thread) ----------------
__global__ __launch_bounds__(256) void k0_cvt(const float* __restrict__ src,
                                              unsigned short* __restrict__ dst)
{
    size_t i = (size_t)blockIdx.x * 256 + threadIdx.x;
    float4 v = reinterpret_cast<const float4*>(src)[i];
    unsigned short o[4] = {f2bf(v.x), f2bf(v.y), f2bf(v.z), f2bf(v.w)};
    reinterpret_cast<uint2*>(dst)[i] = *reinterpret_cast<uint2*>(&o[0]);
}

// ---------------- K1: projection GEMM, bf16 in, transposed + mass-scaled out ----------------
// C[m=c][n=b*N+j] = sum_k Wc16[m][k]*ch16[n][k];  M=2048, N=8192, K=512
__global__ __launch_bounds__(256, 2) void k1_proj(const unsigned short* __restrict__ wc16,  // [2048][512]
                                                  const unsigned short* __restrict__ ch16,  // [8192][512]
                                                  const float* __restrict__ mass,
                                                  unsigned short* __restrict__ projm_t)     // [2048][8192]
{
    __shared__ alignas(16) unsigned short As[128 * 32];
    __shared__ alignas(16) unsigned short Bs[128 * 32];
    const int tid = threadIdx.x, lane = tid & 63, wid = tid >> 6;
    const int q = lane >> 4, l15 = lane & 15;
    const int m0 = blockIdx.y * 128, n0 = blockIdx.x * 128;
    const int wm = (wid & 1) * 64, wn = (wid >> 1) * 64;

    f32x4 acc[4][4];
#pragma unroll
    for (int i = 0; i < 4; i++)
#pragma unroll
        for (int j = 0; j < 4; j++) acc[i][j] = (f32x4){0.f, 0.f, 0.f, 0.f};

    for (int k0 = 0; k0 < 512; k0 += 32) {
        __syncthreads();
#pragma unroll
        for (int q4 = 0; q4 < 4; q4++) {
            int chunk = q4 * 256 + tid;
            int w = chunk & 511, row = w >> 2, c4 = w & 3;
            if (chunk < 512)
                g2l16(&wc16[(size_t)(m0 + row) * 512 + k0 + c4 * 8], &As[w * 8]);
            else
                g2l16(&ch16[(size_t)(n0 + row) * 512 + k0 + c4 * 8], &Bs[w * 8]);
        }
        __syncthreads();
        bf16x8 af[4], bfr[4];
#pragma unroll
        for (int it = 0; it < 4; it++)
            af[it] = *reinterpret_cast<const bf16x8*>(&As[(wm + it * 16 + l15) * 32 + q * 8]);
#pragma unroll
        for (int ct = 0; ct < 4; ct++)
            bfr[ct] = *reinterpret_cast<const bf16x8*>(&Bs[(wn + ct * 16 + l15) * 32 + q * 8]);
#pragma unroll
        for (int it = 0; it < 4; it++)
#pragma unroll
            for (int ct = 0; ct < 4; ct++)
                acc[it][ct] = __builtin_amdgcn_mfma_f32_16x16x32_bf16(af[it], bfr[ct], acc[it][ct], 0, 0, 0);
    }
#pragma unroll
    for (int ct = 0; ct < 4; ct++) {
        int n = n0 + wn + ct * 16 + l15;
        float mf = mass[n];
#pragma unroll
        for (int it = 0; it < 4; it++) {
            int mrow = m0 + wm + it * 16 + q * 4;
#pragma unroll
            for (int r = 0; r < 4; r++)
                projm_t[(size_t)(mrow + r) * 8192 + n] = f2bf(acc[it][ct][r] * mf);
        }
    }
}

// ---------------- K2: fused Gram + exp + field GEMM, j-tile 64 ----------------
// grid (32 i-tiles, 8 c-tiles, 4 b)
__global__ __launch_bounds__(256, 2) void k2_field(const unsigned short* __restrict__ posA,
                                                   const unsigned short* __restrict__ posB1,
                                                   const unsigned short* __restrict__ posB2,
                                                   const float* __restrict__ rsq,
                                                   const float* __restrict__ logbw,
                                                   const unsigned short* __restrict__ projm_t,
                                                   unsigned short* __restrict__ field)
{
    __shared__ alignas(16) unsigned short Bs[2][256 * 32];  // 32 KB
    __shared__ alignas(16) unsigned short pB1[2][32 * 32];  // 4 KB
    __shared__ alignas(16) unsigned short pB2[2][32 * 32];  // 4 KB
    __shared__ alignas(16) unsigned short Wl[2][64 * 40];   // 10 KB

    const int tid = threadIdx.x, lane = tid & 63, wid = tid >> 6;
    const int q = lane >> 4, l15 = lane & 15;
    const int b = blockIdx.z, i0 = blockIdx.x * 64, c0 = blockIdx.y * 256;
    const int kb = c0 >> 9;
    const float bw = __expf(logbw[kb]);
    const float s2 = -1.4426950408889634f / (2.0f * bw + 1e-8f);  // w = exp2(dist2*s2)
    const float c2 = -2.0f * s2;

    // loop-invariant Gram A-frag + ri values (direct global, L1/L2-hit)
    const bf16x8 afG = *reinterpret_cast<const bf16x8*>(
        &posA[(size_t)(b * 2048 + i0 + wid * 16 + l15) * 32 + q * 8]);
    float riv[4];
#pragma unroll
    for (int r = 0; r < 4; r++) riv[r] = rsq[b * 2048 + i0 + wid * 16 + q * 4 + r];

    f32x4 acc[4][4];
#pragma unroll
    for (int i = 0; i < 4; i++)
#pragma unroll
        for (int j = 0; j < 4; j++) acc[i][j] = (f32x4){0.f, 0.f, 0.f, 0.f};

    for (int j0 = 0; j0 < 2048; j0 += 64) {
        __syncthreads();  // previous field-MFMA done with Bs/Wl
        {   // stage Bs: 2 subtiles x 256 rows x 32 bf16 = 2048 chunks of 16B (8/thread)
            const size_t gb = (size_t)c0 * 8192 + b * 2048 + j0;
#pragma unroll
            for (int q8 = 0; q8 < 8; q8++) {
                int chunk = q8 * 256 + tid;
                int s = chunk >> 10, w1 = chunk & 1023;
                g2l16(&projm_t[gb + (size_t)(w1 >> 2) * 8192 + s * 32 + (w1 & 3) * 8],
                      &Bs[s][w1 * 8]);
            }
        }
        {   // stage pB1/pB2: 512 chunks (2/thread)
            const size_t gp = (size_t)(b * 2048 + j0) * 32;
#pragma unroll
            for (int q2 = 0; q2 < 2; q2++) {
                int chunk = q2 * 256 + tid;
                int w = chunk & 255, s = w >> 7, w2 = w & 127;
                if (chunk < 256)
                    g2l16(&posB1[gp + s * 1024 + w2 * 8], &pB1[s][w2 * 8]);
                else
                    g2l16(&posB2[gp + s * 1024 + w2 * 8], &pB2[s][w2 * 8]);
            }
        }
        __syncthreads();  // staging visible
        // Gram + exp -> Wl  (wave wid computes i-rows wid*16..wid*16+15)
#pragma unroll
        for (int s = 0; s < 2; s++) {
#pragma unroll
            for (int jt2 = 0; jt2 < 2; jt2++) {
                bf16x8 b2 = *reinterpret_cast<const bf16x8*>(&pB2[s][(jt2 * 16 + l15) * 32 + q * 8]);
                bf16x8 b1 = *reinterpret_cast<const bf16x8*>(&pB1[s][(jt2 * 16 + l15) * 32 + q * 8]);
                f32x4 g = (f32x4){0.f, 0.f, 0.f, 0.f};
                g = __builtin_amdgcn_mfma_f32_16x16x32_bf16(afG, b2, g, 0, 0, 0);
                g = __builtin_amdgcn_mfma_f32_16x16x32_bf16(afG, b1, g, 0, 0, 0);
                int j = s * 32 + jt2 * 16 + l15;
                float rj = rsq[b * 2048 + j0 + j];
#pragma unroll
                for (int r = 0; r < 4; r++) {
                    float x = __builtin_fmaf(g[r], c2, (riv[r] + rj) * s2);
                    Wl[s][(wid * 16 + q * 4 + r) * 40 + (jt2 * 16 + l15)] =
                        f2bf(__builtin_amdgcn_exp2f(x));
                }
            }
        }
        __syncthreads();  // Wl visible to all waves
        // field MFMA: 2 subtiles x 16 = 32 MFMAs/wave
#pragma unroll
        for (int s = 0; s < 2; s++) {
            bf16x8 af[4], bfr[4];
#pragma unroll
            for (int it = 0; it < 4; it++)
                af[it] = *reinterpret_cast<const bf16x8*>(&Wl[s][(it * 16 + l15) * 40 + q * 8]);
#pragma unroll
            for (int ct = 0; ct < 4; ct++)
                bfr[ct] = *reinterpret_cast<const bf16x8*>(&Bs[s][(wid * 64 + ct * 16 + l15) * 32 + q * 8]);
#pragma unroll
            for (int it = 0; it < 4; it++)
#pragma unroll
                for (int ct = 0; ct < 4; ct++)
                    acc[it][ct] = __builtin_amdgcn_mfma_f32_16x16x32_bf16(af[it], bfr[ct], acc[it][ct], 0, 0, 0);
        }
    }
#pragma unroll
    for (int it = 0; it < 4; it++) {
#pragma unroll
        for (int ct = 0; ct < 4; ct++) {
            int gi = b * 2048 + i0 + it * 16 + q * 4;
            int gc = c0 + wid * 64 + ct * 16 + l15;
#pragma unroll
            for (int r = 0; r < 4; r++)
                field[(size_t)(gi + r) * 2048 + gc] = f2bf(acc[it][ct][r]);
        }
    }
}

// ---------------- K3: combine GEMM, 128m x 64n blocks, fp32 out ----------------
// C[m=b*N+i][n=dout] = sum_c field[m][c]*wcb16[n][c]; M=8192, N=512, K=2048
__global__ __launch_bounds__(256, 2) void k3_combine(const unsigned short* __restrict__ field, // [8192][2048]
                                                     const unsigned short* __restrict__ wcb16, // [512][2048]
                                                     float* __restrict__ out)                  // [8192][512]
{
    __shared__ alignas(16) unsigned short As[128 * 32];  // 8 KB
    __shared__ alignas(16) unsigned short Bs[64 * 32];   // 4 KB
    const int tid = threadIdx.x, lane = tid & 63, wid = tid >> 6;
    const int q = lane >> 4, l15 = lane & 15;
    const int m0 = blockIdx.y * 128, n0 = blockIdx.x * 64;
    const int wm = wid * 32;

    f32x4 acc[2][4];
#pragma unroll
    for (int i = 0; i < 2; i++)
#pragma unroll
        for (int j = 0; j < 4; j++) acc[i][j] = (f32x4){0.f, 0.f, 0.f, 0.f};

    for (int k0 = 0; k0 < 2048; k0 += 32) {
        __syncthreads();
#pragma unroll
        for (int q3 = 0; q3 < 3; q3++) {
            int chunk = q3 * 256 + tid;
            if (chunk < 512) {
                int row = chunk >> 2, c4 = chunk & 3;
                g2l16(&field[(size_t)(m0 + row) * 2048 + k0 + c4 * 8], &As[chunk * 8]);
            } else {
                int w = chunk - 512, row = w >> 2, c4 = w & 3;
                g2l16(&wcb16[(size_t)(n0 + row) * 2048 + k0 + c4 * 8], &Bs[w * 8]);
            }
        }
        __syncthreads();
        bf16x8 af[2], bfr[4];
#pragma unroll
        for (int it = 0; it < 2; it++)
            af[it] = *reinterpret_cast<const bf16x8*>(&As[(wm + it * 16 + l15) * 32 + q * 8]);
#pragma unroll
        for (int ct = 0; ct < 4; ct++)
            bfr[ct] = *reinterpret_cast<const bf16x8*>(&Bs[(ct * 16 + l15) * 32 + q * 8]);
#pragma unroll
        for (int it = 0; it < 2; it++)
#pragma unroll
            for (int ct = 0; ct < 4; ct++)
                acc[it][ct] = __builtin_amdgcn_mfma_f32_16x16x32_bf16(af[it], bfr[ct], acc[it][ct], 0, 0, 0);
    }
#pragma unroll
    for (int it = 0; it < 2; it++) {
#pragma unroll
        for (int ct = 0; ct < 4; ct++) {
            int m = m0 + wm + it * 16 + q * 4;
            int n = n0 + ct * 16 + l15;
#pragma unroll
            for (int r = 0; r < 4; r++)
                out[(size_t)(m + r) * 512 + n] = acc[it][ct][r];
        }
    }
}

// ---------------- K4: LayerNorm in place ----------------
__global__ __launch_bounds__(256) void k4_ln(float* __restrict__ out,
                                             const float* __restrict__ gamma,
                                             const float* __restrict__ beta)
{
    __shared__ float red[8];
    const int row = blockIdx.x, tid = threadIdx.x;
    float2 x = *reinterpret_cast<const float2*>(&out[(size_t)row * 512 + tid * 2]);
    float s = x.x + x.y;
    float ss = x.x * x.x + x.y * x.y;
#pragma unroll
    for (int off = 32; off > 0; off >>= 1) {
        s += __shfl_down(s, off);
        ss += __shfl_down(ss, off);
    }
    int wid = tid >> 6;
    if ((tid & 63) == 0) { red[wid * 2] = s; red[wid * 2 + 1] = ss; }
    __syncthreads();
    s = red[0] + red[2] + red[4] + red[6];
    ss = red[1] + red[3] + red[5] + red[7];
    float mean = s * (1.f / 512.f);
    float var = ss * (1.f / 512.f) - mean * mean;
    float inv = rsqrtf(var + 1e-5f);
    float g0 = gamma[tid * 2], g1 = gamma[tid * 2 + 1];
    float b0 = beta[tid * 2], b1 = beta[tid * 2 + 1];
    float2 o;
    o.x = (x.x - mean) * inv * g0 + b0;
    o.y = (x.y - mean) * inv * g1 + b1;
    *reinterpret_cast<float2*>(&out[(size_t)row * 512 + tid * 2]) = o;
}

extern "C" void kernel_launch(void* const* d_in, const int* in_sizes, int n_in,
                              void* d_out, int out_size, void* d_ws, size_t ws_size,
                              hipStream_t stream)
{
    const float* charge   = (const float*)d_in[0];
    const float* position = (const float*)d_in[1];
    const float* mass     = (const float*)d_in[2];
    const float* logbw    = (const float*)d_in[3];
    const float* Wc       = (const float*)d_in[4];
    const float* Wcb      = (const float*)d_in[5];
    const float* gamma    = (const float*)d_in[6];
    const float* beta     = (const float*)d_in[7];

    // ws layout: [0,32MB) projm_t (later aliased by wcb16) | [32,64MB) field (earlier aliased by ch16+wc16)
    unsigned short* projm_t = (unsigned short*)d_ws;
    unsigned short* field   = projm_t + (size_t)2048 * 8192;
    unsigned short* wcb16   = projm_t;                         // written after K2 (projm_t dead)
    unsigned short* ch16    = field;                           // written before K1, dead before K2 writes field
    unsigned short* wc16    = field + (size_t)8192 * 512;
    // d_out as scratch for pos-derived arrays (dead before K3 writes out)
    unsigned short* posA  = (unsigned short*)d_out;            // 8192*32
    unsigned short* posB1 = posA + (size_t)8192 * 32;
    unsigned short* posB2 = posB1 + (size_t)8192 * 32;
    float* rsq = (float*)(posB2 + (size_t)8192 * 32);          // 8192 floats
    float* out = (float*)d_out;

    k0_pos<<<32, 256, 0, stream>>>(position, posA, posB1, posB2, rsq);
    k0_cvt<<<4096, 256, 0, stream>>>(charge, ch16);            // 8192*512
    k0_cvt<<<1024, 256, 0, stream>>>(Wc, wc16);                // 2048*512
    k1_proj<<<dim3(64, 16), 256, 0, stream>>>(wc16, ch16, mass, projm_t);
    k2_field<<<dim3(32, 8, 4), 256, 0, stream>>>(posA, posB1, posB2, rsq, logbw, projm_t, field);
    k0_cvt<<<1024, 256, 0, stream>>>(Wcb, wcb16);              // 512*2048
    k3_combine<<<dim3(8, 64), 256, 0, stream>>>(field, wcb16, out);
    k4_ln<<<8192, 256, 0, stream>>>(out, gamma, beta);
}

// Round 4
// 263.174 us; speedup vs baseline: 2.0103x; 1.1429x over previous
//
#include <hip/hip_runtime.h>

// ParticleKernel: B=4, N=2048, D=512, P=16, K=4
// K0p: pos -> hi/lo bf16 splits + rsq=|p|^2 (in d_out scratch)
// K0c: fp32 -> bf16 bulk converts
// K1 : projm_t[c][b*N+j] = bf16( mass * charge @ Wc^T )
// K2 : field[b*N+i][c] = bf16( sum_j exp2(s2*dist2) * projm_t[c][j] ); dist2 via MFMA Gram hi/lo
//      tiles 128i x 256c, XCD-aware mapping: each XCD owns 4 (c,b) slices -> projm L2-resident
// K3 : out = field @ Wcb^T (fp32 into d_out), 64m x 128n tiles
// K4 : LayerNorm in place.

typedef __bf16 bf16x8 __attribute__((ext_vector_type(8)));
typedef float f32x4 __attribute__((ext_vector_type(4)));

__device__ __forceinline__ unsigned short f2bf(float f) {
    unsigned u = __float_as_uint(f);
    unsigned r = (u + 0x7fffu + ((u >> 16) & 1u)) >> 16;
    return (unsigned short)r;
}
__device__ __forceinline__ float bf2f(unsigned short h) {
    return __uint_as_float(((unsigned)h) << 16);
}
__device__ __forceinline__ void g2l16(const unsigned short* g, unsigned short* l) {
    __builtin_amdgcn_global_load_lds(
        (const __attribute__((address_space(1))) unsigned int*)g,
        (__attribute__((address_space(3))) unsigned int*)l, 16, 0, 0);
}

// ---------------- K0p: position preprocess ----------------
__global__ __launch_bounds__(256) void k0_pos(const float* __restrict__ pos,
                                              unsigned short* __restrict__ posA,
                                              unsigned short* __restrict__ posB1,
                                              unsigned short* __restrict__ posB2,
                                              float* __restrict__ rsq)
{
    const int row = blockIdx.x * 256 + threadIdx.x;  // 0..8191
    const float* src = &pos[(size_t)row * 16];
    float p[16];
#pragma unroll
    for (int cc = 0; cc < 4; cc++) {
        float4 v = *reinterpret_cast<const float4*>(&src[cc * 4]);
        p[cc * 4 + 0] = v.x; p[cc * 4 + 1] = v.y; p[cc * 4 + 2] = v.z; p[cc * 4 + 3] = v.w;
    }
    float r = 0.f;
    unsigned short h[16], lo[16], z[8] = {0, 0, 0, 0, 0, 0, 0, 0};
#pragma unroll
    for (int d = 0; d < 16; d++) {
        r = __builtin_fmaf(p[d], p[d], r);
        h[d] = f2bf(p[d]);
        lo[d] = f2bf(p[d] - bf2f(h[d]));
    }
    rsq[row] = r;
    size_t o = (size_t)row * 32;
    *reinterpret_cast<int4*>(&posA[o + 0])   = *reinterpret_cast<int4*>(&h[0]);
    *reinterpret_cast<int4*>(&posA[o + 8])   = *reinterpret_cast<int4*>(&h[8]);
    *reinterpret_cast<int4*>(&posA[o + 16])  = *reinterpret_cast<int4*>(&lo[0]);
    *reinterpret_cast<int4*>(&posA[o + 24])  = *reinterpret_cast<int4*>(&lo[8]);
    *reinterpret_cast<int4*>(&posB1[o + 0])  = *reinterpret_cast<int4*>(&h[0]);
    *reinterpret_cast<int4*>(&posB1[o + 8])  = *reinterpret_cast<int4*>(&h[8]);
    *reinterpret_cast<int4*>(&posB1[o + 16]) = *reinterpret_cast<int4*>(&h[0]);
    *reinterpret_cast<int4*>(&posB1[o + 24]) = *reinterpret_cast<int4*>(&h[8]);
    *reinterpret_cast<int4*>(&posB2[o + 0])  = *reinterpret_cast<int4*>(&lo[0]);
    *reinterpret_cast<int4*>(&posB2[o + 8])  = *reinterpret_cast<int4*>(&lo[8]);
    *reinterpret_cast<int4*>(&posB2[o + 16]) = *reinterpret_cast<int4*>(&z[0]);
    *reinterpret_cast<int4*>(&posB2[o + 24]) = *reinterpret_cast<int4*>(&z[0]);
}

// ---------------- K0c: bulk fp32 -> bf16 convert ----------------
__global__ __launch_bounds__(256) void k0_cvt(const float* __restrict__ src,
                                              unsigned short* __restrict__ dst)
{
    size_t i = (size_t)blockIdx.x * 256 + threadIdx.x;
    float4 v = reinterpret_cast<const float4*>(src)[i];
    unsigned short o[4] = {f2bf(v.x), f2bf(v.y), f2bf(v.z), f2bf(v.w)};
    reinterpret_cast<uint2*>(dst)[i] = *reinterpret_cast<uint2*>(&o[0]);
}

// ---------------- K1: projection GEMM ----------------
// C[m=c][n=b*N+j] = sum_k Wc16[m][k]*ch16[n][k];  M=2048, N=8192, K=512
__global__ __launch_bounds__(256, 2) void k1_proj(const unsigned short* __restrict__ wc16,
                                                  const unsigned short* __restrict__ ch16,
                                                  const float* __restrict__ mass,
                                                  unsigned short* __restrict__ projm_t)
{
    __shared__ alignas(16) unsigned short As[128 * 32];
    __shared__ alignas(16) unsigned short Bs[128 * 32];
    const int tid = threadIdx.x, lane = tid & 63, wid = tid >> 6;
    const int q = lane >> 4, l15 = lane & 15;
    const int m0 = blockIdx.y * 128, n0 = blockIdx.x * 128;
    const int wm = (wid & 1) * 64, wn = (wid >> 1) * 64;

    f32x4 acc[4][4];
#pragma unroll
    for (int i = 0; i < 4; i++)
#pragma unroll
        for (int j = 0; j < 4; j++) acc[i][j] = (f32x4){0.f, 0.f, 0.f, 0.f};

    for (int k0 = 0; k0 < 512; k0 += 32) {
        __syncthreads();
#pragma unroll
        for (int q4 = 0; q4 < 4; q4++) {
            int chunk = q4 * 256 + tid;
            int w = chunk & 511, row = w >> 2, c4 = w & 3;
            if (chunk < 512)
                g2l16(&wc16[(size_t)(m0 + row) * 512 + k0 + c4 * 8], &As[w * 8]);
            else
                g2l16(&ch16[(size_t)(n0 + row) * 512 + k0 + c4 * 8], &Bs[w * 8]);
        }
        __syncthreads();
        bf16x8 af[4], bfr[4];
#pragma unroll
        for (int it = 0; it < 4; it++)
            af[it] = *reinterpret_cast<const bf16x8*>(&As[(wm + it * 16 + l15) * 32 + q * 8]);
#pragma unroll
        for (int ct = 0; ct < 4; ct++)
            bfr[ct] = *reinterpret_cast<const bf16x8*>(&Bs[(wn + ct * 16 + l15) * 32 + q * 8]);
#pragma unroll
        for (int it = 0; it < 4; it++)
#pragma unroll
            for (int ct = 0; ct < 4; ct++)
                acc[it][ct] = __builtin_amdgcn_mfma_f32_16x16x32_bf16(af[it], bfr[ct], acc[it][ct], 0, 0, 0);
    }
#pragma unroll
    for (int ct = 0; ct < 4; ct++) {
        int n = n0 + wn + ct * 16 + l15;
        float mf = mass[n];
#pragma unroll
        for (int it = 0; it < 4; it++) {
            int mrow = m0 + wm + it * 16 + q * 4;
#pragma unroll
            for (int r = 0; r < 4; r++)
                projm_t[(size_t)(mrow + r) * 8192 + n] = f2bf(acc[it][ct][r] * mf);
        }
    }
}

// ---------------- K2: fused Gram + exp + field GEMM, 128i x 256c ----------------
// 1-D grid 512, XCD-aware decode: xcd = L&7 owns 4 (c,b) slices; 16 i-blocks per slice
__global__ __launch_bounds__(256, 2) void k2_field(const unsigned short* __restrict__ posA,
                                                   const unsigned short* __restrict__ posB1,
                                                   const unsigned short* __restrict__ posB2,
                                                   const float* __restrict__ rsq,
                                                   const float* __restrict__ logbw,
                                                   const unsigned short* __restrict__ projm_t,
                                                   unsigned short* __restrict__ field)
{
    __shared__ alignas(16) unsigned short Bs[2][256 * 32];  // 32 KB
    __shared__ alignas(16) unsigned short pB1[2][32 * 32];  // 4 KB
    __shared__ alignas(16) unsigned short pB2[2][32 * 32];  // 4 KB
    __shared__ alignas(16) unsigned short Wl[2][128 * 40];  // 20 KB

    const int tid = threadIdx.x, lane = tid & 63, wid = tid >> 6;
    const int q = lane >> 4, l15 = lane & 15;
    // XCD-aware decode (assumes round-robin workgroup->XCD by linear id; perf-only heuristic)
    const int L = blockIdx.x;
    const int xcd = L & 7, idx = L >> 3;
    const int i_t = idx & 15, cb = xcd * 4 + (idx >> 4);
    const int c0 = (cb & 7) * 256, b = cb >> 3;
    const int i0 = i_t * 128;
    const int kb = c0 >> 9;
    const float bw = __expf(logbw[kb]);
    const float s2 = -1.4426950408889634f / (2.0f * bw + 1e-8f);  // w = exp2(dist2*s2)
    const float c2 = -2.0f * s2;

    // loop-invariant Gram A-frags + ri values (wave wid owns i-rows [wid*32, wid*32+32))
    bf16x8 afG[2];
    float riv[2][4];
#pragma unroll
    for (int t = 0; t < 2; t++) {
        afG[t] = *reinterpret_cast<const bf16x8*>(
            &posA[(size_t)(b * 2048 + i0 + wid * 32 + t * 16 + l15) * 32 + q * 8]);
#pragma unroll
        for (int r = 0; r < 4; r++)
            riv[t][r] = rsq[b * 2048 + i0 + wid * 32 + t * 16 + q * 4 + r];
    }

    // field wave mapping: wave -> 64i x 128c; wo_i = (wid>>1)*64, wo_c = (wid&1)*128
    const int wo_i = (wid >> 1) * 64, wo_c = (wid & 1) * 128;

    f32x4 acc[4][8];
#pragma unroll
    for (int i = 0; i < 4; i++)
#pragma unroll
        for (int j = 0; j < 8; j++) acc[i][j] = (f32x4){0.f, 0.f, 0.f, 0.f};

    for (int j0 = 0; j0 < 2048; j0 += 64) {
        // prefetch rj for this iteration (out of the dependent chain)
        float rjv[2][2];
#pragma unroll
        for (int s = 0; s < 2; s++)
#pragma unroll
            for (int jt2 = 0; jt2 < 2; jt2++)
                rjv[s][jt2] = rsq[b * 2048 + j0 + s * 32 + jt2 * 16 + l15];

        __syncthreads();  // previous field-MFMA done with Bs/Wl
        {   // stage Bs: 2 subtiles x 256 rows x 32 bf16 = 2048 chunks (8/thread)
            const size_t gb = (size_t)c0 * 8192 + b * 2048 + j0;
#pragma unroll
            for (int q8 = 0; q8 < 8; q8++) {
                int chunk = q8 * 256 + tid;
                int s = chunk >> 10, w1 = chunk & 1023;
                g2l16(&projm_t[gb + (size_t)(w1 >> 2) * 8192 + s * 32 + (w1 & 3) * 8],
                      &Bs[s][w1 * 8]);
            }
        }
        {   // stage pB1/pB2: 512 chunks (2/thread)
            const size_t gp = (size_t)(b * 2048 + j0) * 32;
#pragma unroll
            for (int q2 = 0; q2 < 2; q2++) {
                int chunk = q2 * 256 + tid;
                int w = chunk & 255, s = w >> 7, w2 = w & 127;
                if (chunk < 256)
                    g2l16(&posB1[gp + s * 1024 + w2 * 8], &pB1[s][w2 * 8]);
                else
                    g2l16(&posB2[gp + s * 1024 + w2 * 8], &pB2[s][w2 * 8]);
            }
        }
        __syncthreads();  // staging visible
        // Gram + exp -> Wl rows [wid*32, wid*32+32)
#pragma unroll
        for (int s = 0; s < 2; s++) {
#pragma unroll
            for (int jt2 = 0; jt2 < 2; jt2++) {
                bf16x8 b2 = *reinterpret_cast<const bf16x8*>(&pB2[s][(jt2 * 16 + l15) * 32 + q * 8]);
                bf16x8 b1 = *reinterpret_cast<const bf16x8*>(&pB1[s][(jt2 * 16 + l15) * 32 + q * 8]);
#pragma unroll
                for (int t = 0; t < 2; t++) {
                    f32x4 g = (f32x4){0.f, 0.f, 0.f, 0.f};
                    g = __builtin_amdgcn_mfma_f32_16x16x32_bf16(afG[t], b2, g, 0, 0, 0);
                    g = __builtin_amdgcn_mfma_f32_16x16x32_bf16(afG[t], b1, g, 0, 0, 0);
                    float rj = rjv[s][jt2];
#pragma unroll
                    for (int r = 0; r < 4; r++) {
                        float x = __builtin_fmaf(g[r], c2, (riv[t][r] + rj) * s2);
                        Wl[s][(wid * 32 + t * 16 + q * 4 + r) * 40 + (jt2 * 16 + l15)] =
                            f2bf(__builtin_amdgcn_exp2f(x));
                    }
                }
            }
        }
        __syncthreads();  // Wl visible to all waves
        // field MFMA: wave computes 64i x 128c; per s: 4 af + 8 bfr reads, 32 MFMAs
#pragma unroll
        for (int s = 0; s < 2; s++) {
            bf16x8 af[4], bfr[8];
#pragma unroll
            for (int it = 0; it < 4; it++)
                af[it] = *reinterpret_cast<const bf16x8*>(&Wl[s][(wo_i + it * 16 + l15) * 40 + q * 8]);
#pragma unroll
            for (int ct = 0; ct < 8; ct++)
                bfr[ct] = *reinterpret_cast<const bf16x8*>(&Bs[s][(wo_c + ct * 16 + l15) * 32 + q * 8]);
#pragma unroll
            for (int it = 0; it < 4; it++)
#pragma unroll
                for (int ct = 0; ct < 8; ct++)
                    acc[it][ct] = __builtin_amdgcn_mfma_f32_16x16x32_bf16(af[it], bfr[ct], acc[it][ct], 0, 0, 0);
        }
    }
#pragma unroll
    for (int it = 0; it < 4; it++) {
#pragma unroll
        for (int ct = 0; ct < 8; ct++) {
            int gi = b * 2048 + i0 + wo_i + it * 16 + q * 4;
            int gc = c0 + wo_c + ct * 16 + l15;
#pragma unroll
            for (int r = 0; r < 4; r++)
                field[(size_t)(gi + r) * 2048 + gc] = f2bf(acc[it][ct][r]);
        }
    }
}

// ---------------- K3: combine GEMM, 64m x 128n tiles, fp32 out ----------------
// C[m=b*N+i][n=dout] = sum_c field[m][c]*wcb16[n][c]; M=8192, N=512, K=2048
__global__ __launch_bounds__(256, 2) void k3_combine(const unsigned short* __restrict__ field,
                                                     const unsigned short* __restrict__ wcb16,
                                                     float* __restrict__ out)
{
    __shared__ alignas(16) unsigned short As[64 * 32];   // 4 KB
    __shared__ alignas(16) unsigned short Bs[128 * 32];  // 8 KB
    const int tid = threadIdx.x, lane = tid & 63, wid = tid >> 6;
    const int q = lane >> 4, l15 = lane & 15;
    const int m0 = blockIdx.y * 64, n0 = blockIdx.x * 128;
    const int wn = wid * 32;

    f32x4 acc[4][2];
#pragma unroll
    for (int i = 0; i < 4; i++)
#pragma unroll
        for (int j = 0; j < 2; j++) acc[i][j] = (f32x4){0.f, 0.f, 0.f, 0.f};

    for (int k0 = 0; k0 < 2048; k0 += 32) {
        __syncthreads();
#pragma unroll
        for (int q3 = 0; q3 < 3; q3++) {
            int chunk = q3 * 256 + tid;
            if (chunk < 256) {
                int row = chunk >> 2, c4 = chunk & 3;
                g2l16(&field[(size_t)(m0 + row) * 2048 + k0 + c4 * 8], &As[chunk * 8]);
            } else {
                int w = chunk - 256, row = w >> 2, c4 = w & 3;
                g2l16(&wcb16[(size_t)(n0 + row) * 2048 + k0 + c4 * 8], &Bs[w * 8]);
            }
        }
        __syncthreads();
        bf16x8 af[4], bfr[2];
#pragma unroll
        for (int it = 0; it < 4; it++)
            af[it] = *reinterpret_cast<const bf16x8*>(&As[(it * 16 + l15) * 32 + q * 8]);
#pragma unroll
        for (int ct = 0; ct < 2; ct++)
            bfr[ct] = *reinterpret_cast<const bf16x8*>(&Bs[(wn + ct * 16 + l15) * 32 + q * 8]);
#pragma unroll
        for (int it = 0; it < 4; it++)
#pragma unroll
            for (int ct = 0; ct < 2; ct++)
                acc[it][ct] = __builtin_amdgcn_mfma_f32_16x16x32_bf16(af[it], bfr[ct], acc[it][ct], 0, 0, 0);
    }
#pragma unroll
    for (int it = 0; it < 4; it++) {
#pragma unroll
        for (int ct = 0; ct < 2; ct++) {
            int m = m0 + it * 16 + q * 4;
            int n = n0 + wn + ct * 16 + l15;
#pragma unroll
            for (int r = 0; r < 4; r++)
                out[(size_t)(m + r) * 512 + n] = acc[it][ct][r];
        }
    }
}

// ---------------- K4: LayerNorm in place ----------------
__global__ __launch_bounds__(256) void k4_ln(float* __restrict__ out,
                                             const float* __restrict__ gamma,
                                             const float* __restrict__ beta)
{
    __shared__ float red[8];
    const int row = blockIdx.x, tid = threadIdx.x;
    float2 x = *reinterpret_cast<const float2*>(&out[(size_t)row * 512 + tid * 2]);
    float s = x.x + x.y;
    float ss = x.x * x.x + x.y * x.y;
#pragma unroll
    for (int off = 32; off > 0; off >>= 1) {
        s += __shfl_down(s, off);
        ss += __shfl_down(ss, off);
    }
    int wid = tid >> 6;
    if ((tid & 63) == 0) { red[wid * 2] = s; red[wid * 2 + 1] = ss; }
    __syncthreads();
    s = red[0] + red[2] + red[4] + red[6];
    ss = red[1] + red[3] + red[5] + red[7];
    float mean = s * (1.f / 512.f);
    float var = ss * (1.f / 512.f) - mean * mean;
    float inv = rsqrtf(var + 1e-5f);
    float g0 = gamma[tid * 2], g1 = gamma[tid * 2 + 1];
    float b0 = beta[tid * 2], b1 = beta[tid * 2 + 1];
    float2 o;
    o.x = (x.x - mean) * inv * g0 + b0;
    o.y = (x.y - mean) * inv * g1 + b1;
    *reinterpret_cast<float2*>(&out[(size_t)row * 512 + tid * 2]) = o;
}

extern "C" void kernel_launch(void* const* d_in, const int* in_sizes, int n_in,
                              void* d_out, int out_size, void* d_ws, size_t ws_size,
                              hipStream_t stream)
{
    const float* charge   = (const float*)d_in[0];
    const float* position = (const float*)d_in[1];
    const float* mass     = (const float*)d_in[2];
    const float* logbw    = (const float*)d_in[3];
    const float* Wc       = (const float*)d_in[4];
    const float* Wcb      = (const float*)d_in[5];
    const float* gamma    = (const float*)d_in[6];
    const float* beta     = (const float*)d_in[7];

    // ws layout: [0,32MB) projm_t (later aliased by wcb16) | [32,64MB) field (earlier aliased by ch16+wc16)
    unsigned short* projm_t = (unsigned short*)d_ws;
    unsigned short* field   = projm_t + (size_t)2048 * 8192;
    unsigned short* wcb16   = projm_t;                         // written after K2 (projm_t dead)
    unsigned short* ch16    = field;                           // dead before K2 writes field
    unsigned short* wc16    = field + (size_t)8192 * 512;
    // d_out as scratch for pos-derived arrays (dead before K3 writes out)
    unsigned short* posA  = (unsigned short*)d_out;            // 8192*32
    unsigned short* posB1 = posA + (size_t)8192 * 32;
    unsigned short* posB2 = posB1 + (size_t)8192 * 32;
    float* rsq = (float*)(posB2 + (size_t)8192 * 32);          // 8192 floats
    float* out = (float*)d_out;

    k0_pos<<<32, 256, 0, stream>>>(position, posA, posB1, posB2, rsq);
    k0_cvt<<<4096, 256, 0, stream>>>(charge, ch16);            // 8192*512
    k0_cvt<<<1024, 256, 0, stream>>>(Wc, wc16);                // 2048*512
    k1_proj<<<dim3(64, 16), 256, 0, stream>>>(wc16, ch16, mass, projm_t);
    k2_field<<<512, 256, 0, stream>>>(posA, posB1, posB2, rsq, logbw, projm_t, field);
    k0_cvt<<<1024, 256, 0, stream>>>(Wcb, wcb16);              // 512*2048
    k3_combine<<<dim3(4, 128), 256, 0, stream>>>(field, wcb16, out);
    k4_ln<<<8192, 256, 0, stream>>>(out, gamma, beta);
}

// Round 5
// 260.824 us; speedup vs baseline: 2.0284x; 1.0090x over previous
//
#include <hip/hip_runtime.h>

// ParticleKernel: B=4, N=2048, D=512, P=16, K=4
// K0p: pos -> hi/lo bf16 splits + rsq=|p|^2 (in d_out scratch)
// K0c: fp32 -> bf16 bulk converts
// K1 : projm_t[c][b*N+j] = bf16( mass * charge @ Wc^T )           (chunk-swizzled LDS)
// K2 : field[b*N+i][c] = bf16( sum_j exp2(s2*dist2)*projm_t[c][j] ); dist2 via MFMA Gram hi/lo.
//      2-barrier loop: Gram B-frags straight from global (L2), Wl cross-wave via LDS.
//      XCD-aware mapping keeps each XCD's projm slice L2-resident.
// K3 : out = field @ Wcb^T (fp32 into d_out)
// K4 : LayerNorm in place.

typedef __bf16 bf16x8 __attribute__((ext_vector_type(8)));
typedef float f32x4 __attribute__((ext_vector_type(4)));

__device__ __forceinline__ unsigned short f2bf(float f) {
    unsigned u = __float_as_uint(f);
    unsigned r = (u + 0x7fffu + ((u >> 16) & 1u)) >> 16;
    return (unsigned short)r;
}
__device__ __forceinline__ float bf2f(unsigned short h) {
    return __uint_as_float(((unsigned)h) << 16);
}
__device__ __forceinline__ void g2l16(const unsigned short* g, unsigned short* l) {
    __builtin_amdgcn_global_load_lds(
        (const __attribute__((address_space(1))) unsigned int*)g,
        (__attribute__((address_space(3))) unsigned int*)l, 16, 0, 0);
}

// ---------------- K0p: position preprocess ----------------
__global__ __launch_bounds__(256) void k0_pos(const float* __restrict__ pos,
                                              unsigned short* __restrict__ posA,
                                              unsigned short* __restrict__ posB1,
                                              unsigned short* __restrict__ posB2,
                                              float* __restrict__ rsq)
{
    const int row = blockIdx.x * 256 + threadIdx.x;  // 0..8191
    const float* src = &pos[(size_t)row * 16];
    float p[16];
#pragma unroll
    for (int cc = 0; cc < 4; cc++) {
        float4 v = *reinterpret_cast<const float4*>(&src[cc * 4]);
        p[cc * 4 + 0] = v.x; p[cc * 4 + 1] = v.y; p[cc * 4 + 2] = v.z; p[cc * 4 + 3] = v.w;
    }
    float r = 0.f;
    unsigned short h[16], lo[16], z[8] = {0, 0, 0, 0, 0, 0, 0, 0};
#pragma unroll
    for (int d = 0; d < 16; d++) {
        r = __builtin_fmaf(p[d], p[d], r);
        h[d] = f2bf(p[d]);
        lo[d] = f2bf(p[d] - bf2f(h[d]));
    }
    rsq[row] = r;
    size_t o = (size_t)row * 32;
    *reinterpret_cast<int4*>(&posA[o + 0])   = *reinterpret_cast<int4*>(&h[0]);
    *reinterpret_cast<int4*>(&posA[o + 8])   = *reinterpret_cast<int4*>(&h[8]);
    *reinterpret_cast<int4*>(&posA[o + 16])  = *reinterpret_cast<int4*>(&lo[0]);
    *reinterpret_cast<int4*>(&posA[o + 24])  = *reinterpret_cast<int4*>(&lo[8]);
    *reinterpret_cast<int4*>(&posB1[o + 0])  = *reinterpret_cast<int4*>(&h[0]);
    *reinterpret_cast<int4*>(&posB1[o + 8])  = *reinterpret_cast<int4*>(&h[8]);
    *reinterpret_cast<int4*>(&posB1[o + 16]) = *reinterpret_cast<int4*>(&h[0]);
    *reinterpret_cast<int4*>(&posB1[o + 24]) = *reinterpret_cast<int4*>(&h[8]);
    *reinterpret_cast<int4*>(&posB2[o + 0])  = *reinterpret_cast<int4*>(&lo[0]);
    *reinterpret_cast<int4*>(&posB2[o + 8])  = *reinterpret_cast<int4*>(&lo[8]);
    *reinterpret_cast<int4*>(&posB2[o + 16]) = *reinterpret_cast<int4*>(&z[0]);
    *reinterpret_cast<int4*>(&posB2[o + 24]) = *reinterpret_cast<int4*>(&z[0]);
}

// ---------------- K0c: bulk fp32 -> bf16 convert ----------------
__global__ __launch_bounds__(256) void k0_cvt(const float* __restrict__ src,
                                              unsigned short* __restrict__ dst)
{
    size_t i = (size_t)blockIdx.x * 256 + threadIdx.x;
    float4 v = reinterpret_cast<const float4*>(src)[i];
    unsigned short o[4] = {f2bf(v.x), f2bf(v.y), f2bf(v.z), f2bf(v.w)};
    reinterpret_cast<uint2*>(dst)[i] = *reinterpret_cast<uint2*>(&o[0]);
}

// ---------------- K1: projection GEMM (chunk-swizzled LDS) ----------------
// C[m=c][n=b*N+j] = sum_k Wc16[m][k]*ch16[n][k];  M=2048, N=8192, K=512
__global__ __launch_bounds__(256, 2) void k1_proj(const unsigned short* __restrict__ wc16,
                                                  const unsigned short* __restrict__ ch16,
                                                  const float* __restrict__ mass,
                                                  unsigned short* __restrict__ projm_t)
{
    __shared__ alignas(16) unsigned short As[128 * 32];
    __shared__ alignas(16) unsigned short Bs[128 * 32];
    const int tid = threadIdx.x, lane = tid & 63, wid = tid >> 6;
    const int q = lane >> 4, l15 = lane & 15;
    const int sw = (l15 >> 2) & 3;
    const int m0 = blockIdx.y * 128, n0 = blockIdx.x * 128;
    const int wm = (wid & 1) * 64, wn = (wid >> 1) * 64;

    f32x4 acc[4][4];
#pragma unroll
    for (int i = 0; i < 4; i++)
#pragma unroll
        for (int j = 0; j < 4; j++) acc[i][j] = (f32x4){0.f, 0.f, 0.f, 0.f};

    for (int k0 = 0; k0 < 512; k0 += 32) {
        __syncthreads();
#pragma unroll
        for (int q4 = 0; q4 < 4; q4++) {
            int chunk = q4 * 256 + tid;
            int w = chunk & 511, row = w >> 2;
            int gc4 = (w & 3) ^ ((w >> 4) & 3);
            if (chunk < 512)
                g2l16(&wc16[(size_t)(m0 + row) * 512 + k0 + gc4 * 8], &As[w * 8]);
            else
                g2l16(&ch16[(size_t)(n0 + row) * 512 + k0 + gc4 * 8], &Bs[w * 8]);
        }
        __syncthreads();
        bf16x8 af[4], bfr[4];
#pragma unroll
        for (int it = 0; it < 4; it++)
            af[it] = *reinterpret_cast<const bf16x8*>(&As[(wm + it * 16 + l15) * 32 + (q ^ sw) * 8]);
#pragma unroll
        for (int ct = 0; ct < 4; ct++)
            bfr[ct] = *reinterpret_cast<const bf16x8*>(&Bs[(wn + ct * 16 + l15) * 32 + (q ^ sw) * 8]);
#pragma unroll
        for (int it = 0; it < 4; it++)
#pragma unroll
            for (int ct = 0; ct < 4; ct++)
                acc[it][ct] = __builtin_amdgcn_mfma_f32_16x16x32_bf16(af[it], bfr[ct], acc[it][ct], 0, 0, 0);
    }
#pragma unroll
    for (int ct = 0; ct < 4; ct++) {
        int n = n0 + wn + ct * 16 + l15;
        float mf = mass[n];
#pragma unroll
        for (int it = 0; it < 4; it++) {
            int mrow = m0 + wm + it * 16 + q * 4;
#pragma unroll
            for (int r = 0; r < 4; r++)
                projm_t[(size_t)(mrow + r) * 8192 + n] = f2bf(acc[it][ct][r] * mf);
        }
    }
}

// ---------------- K2: fused Gram + exp + field GEMM, 128i x 256c, 2 barriers ----------------
__global__ __launch_bounds__(256, 2) void k2_field(const unsigned short* __restrict__ posA,
                                                   const unsigned short* __restrict__ posB1,
                                                   const unsigned short* __restrict__ posB2,
                                                   const float* __restrict__ rsq,
                                                   const float* __restrict__ logbw,
                                                   const unsigned short* __restrict__ projm_t,
                                                   unsigned short* __restrict__ field)
{
    __shared__ alignas(16) unsigned short Bs[2][256 * 32];  // 32 KB, chunk-swizzled
    __shared__ alignas(16) unsigned short Wl[2][128 * 40];  // 20 KB (40-stride: 16B-aligned rows)

    const int tid = threadIdx.x, lane = tid & 63, wid = tid >> 6;
    const int q = lane >> 4, l15 = lane & 15;
    const int sw = (l15 >> 2) & 3;
    // XCD-aware decode (round-robin workgroup->XCD by linear id; perf heuristic only)
    const int L = blockIdx.x;
    const int xcd = L & 7, idx = L >> 3;
    const int i_t = idx & 15, cb = xcd * 4 + (idx >> 4);
    const int c0 = (cb & 7) * 256, b = cb >> 3;
    const int i0 = i_t * 128;
    const int kb = c0 >> 9;
    const float bw = __expf(logbw[kb]);
    const float s2 = -1.4426950408889634f / (2.0f * bw + 1e-8f);  // w = exp2(dist2*s2)
    const float c2 = -2.0f * s2;
    const int bN = b * 2048;

    // loop-invariant Gram A-frags + ri*s2 (wave wid owns Wl rows [wid*32, wid*32+32))
    bf16x8 afG[2];
    float riS2[2][4];
#pragma unroll
    for (int t = 0; t < 2; t++) {
        afG[t] = *reinterpret_cast<const bf16x8*>(
            &posA[(size_t)(bN + i0 + wid * 32 + t * 16 + l15) * 32 + q * 8]);
#pragma unroll
        for (int r = 0; r < 4; r++)
            riS2[t][r] = rsq[bN + i0 + wid * 32 + t * 16 + q * 4 + r] * s2;
    }

    const int wo_i = (wid >> 1) * 64, wo_c = (wid & 1) * 128;

    f32x4 acc[4][8];
#pragma unroll
    for (int i = 0; i < 4; i++)
#pragma unroll
        for (int j = 0; j < 8; j++) acc[i][j] = (f32x4){0.f, 0.f, 0.f, 0.f};

    for (int j0 = 0; j0 < 2048; j0 += 64) {
        // ---- phase A (regs only, overlaps other waves' field MFMA): Gram + exp ----
        unsigned short wv[2][2][2][4];  // [s][jt2][t][r]
#pragma unroll
        for (int s = 0; s < 2; s++) {
#pragma unroll
            for (int jt2 = 0; jt2 < 2; jt2++) {
                int j = bN + j0 + s * 32 + jt2 * 16 + l15;
                bf16x8 b1 = *reinterpret_cast<const bf16x8*>(&posB1[(size_t)j * 32 + q * 8]);
                bf16x8 b2 = *reinterpret_cast<const bf16x8*>(&posB2[(size_t)j * 32 + q * 8]);
                float rj2 = rsq[j] * s2;
#pragma unroll
                for (int t = 0; t < 2; t++) {
                    f32x4 g = (f32x4){0.f, 0.f, 0.f, 0.f};
                    g = __builtin_amdgcn_mfma_f32_16x16x32_bf16(afG[t], b2, g, 0, 0, 0);
                    g = __builtin_amdgcn_mfma_f32_16x16x32_bf16(afG[t], b1, g, 0, 0, 0);
#pragma unroll
                    for (int r = 0; r < 4; r++) {
                        float x = __builtin_fmaf(g[r], c2, riS2[t][r] + rj2);
                        wv[s][jt2][t][r] = f2bf(__builtin_amdgcn_exp2f(x));
                    }
                }
            }
        }
        __syncthreads();  // B1: previous field MFMA done reading Bs/Wl
        // ---- phase B: publish Wl + stage Bs ----
#pragma unroll
        for (int s = 0; s < 2; s++)
#pragma unroll
            for (int jt2 = 0; jt2 < 2; jt2++)
#pragma unroll
                for (int t = 0; t < 2; t++)
#pragma unroll
                    for (int r = 0; r < 4; r++)
                        Wl[s][(wid * 32 + t * 16 + q * 4 + r) * 40 + jt2 * 16 + l15] =
                            wv[s][jt2][t][r];
        {
            const size_t gb = (size_t)c0 * 8192 + bN + j0;
#pragma unroll
            for (int q8 = 0; q8 < 8; q8++) {
                int chunk = q8 * 256 + tid;
                int s = chunk >> 10, w1 = chunk & 1023;
                int row = w1 >> 2, gc4 = (w1 & 3) ^ ((w1 >> 4) & 3);
                g2l16(&projm_t[gb + (size_t)row * 8192 + s * 32 + gc4 * 8], &Bs[s][w1 * 8]);
            }
        }
        __syncthreads();  // B2: Wl + staging visible
        // ---- phase C: field MFMA ----
#pragma unroll
        for (int s = 0; s < 2; s++) {
            bf16x8 af[4], bfr[8];
#pragma unroll
            for (int it = 0; it < 4; it++)
                af[it] = *reinterpret_cast<const bf16x8*>(&Wl[s][(wo_i + it * 16 + l15) * 40 + q * 8]);
#pragma unroll
            for (int ct = 0; ct < 8; ct++)
                bfr[ct] = *reinterpret_cast<const bf16x8*>(&Bs[s][(wo_c + ct * 16 + l15) * 32 + (q ^ sw) * 8]);
#pragma unroll
            for (int it = 0; it < 4; it++)
#pragma unroll
                for (int ct = 0; ct < 8; ct++)
                    acc[it][ct] = __builtin_amdgcn_mfma_f32_16x16x32_bf16(af[it], bfr[ct], acc[it][ct], 0, 0, 0);
        }
    }
#pragma unroll
    for (int it = 0; it < 4; it++) {
#pragma unroll
        for (int ct = 0; ct < 8; ct++) {
            int gi = bN + i0 + wo_i + it * 16 + q * 4;
            int gc = c0 + wo_c + ct * 16 + l15;
#pragma unroll
            for (int r = 0; r < 4; r++)
                field[(size_t)(gi + r) * 2048 + gc] = f2bf(acc[it][ct][r]);
        }
    }
}

// ---------------- K3: combine GEMM, 64m x 128n tiles (chunk-swizzled), fp32 out ----------------
// C[m=b*N+i][n=dout] = sum_c field[m][c]*wcb16[n][c]; M=8192, N=512, K=2048
__global__ __launch_bounds__(256, 2) void k3_combine(const unsigned short* __restrict__ field,
                                                     const unsigned short* __restrict__ wcb16,
                                                     float* __restrict__ out)
{
    __shared__ alignas(16) unsigned short As[64 * 32];   // 4 KB
    __shared__ alignas(16) unsigned short Bs[128 * 32];  // 8 KB
    const int tid = threadIdx.x, lane = tid & 63, wid = tid >> 6;
    const int q = lane >> 4, l15 = lane & 15;
    const int sw = (l15 >> 2) & 3;
    const int m0 = blockIdx.y * 64, n0 = blockIdx.x * 128;
    const int wn = wid * 32;

    f32x4 acc[4][2];
#pragma unroll
    for (int i = 0; i < 4; i++)
#pragma unroll
        for (int j = 0; j < 2; j++) acc[i][j] = (f32x4){0.f, 0.f, 0.f, 0.f};

    for (int k0 = 0; k0 < 2048; k0 += 32) {
        __syncthreads();
#pragma unroll
        for (int q3 = 0; q3 < 3; q3++) {
            int chunk = q3 * 256 + tid;
            if (chunk < 256) {
                int row = chunk >> 2, gc4 = (chunk & 3) ^ ((chunk >> 4) & 3);
                g2l16(&field[(size_t)(m0 + row) * 2048 + k0 + gc4 * 8], &As[chunk * 8]);
            } else {
                int w = chunk - 256, row = w >> 2, gc4 = (w & 3) ^ ((w >> 4) & 3);
                g2l16(&wcb16[(size_t)(n0 + row) * 2048 + k0 + gc4 * 8], &Bs[w * 8]);
            }
        }
        __syncthreads();
        bf16x8 af[4], bfr[2];
#pragma unroll
        for (int it = 0; it < 4; it++)
            af[it] = *reinterpret_cast<const bf16x8*>(&As[(it * 16 + l15) * 32 + (q ^ sw) * 8]);
#pragma unroll
        for (int ct = 0; ct < 2; ct++)
            bfr[ct] = *reinterpret_cast<const bf16x8*>(&Bs[(wn + ct * 16 + l15) * 32 + (q ^ sw) * 8]);
#pragma unroll
        for (int it = 0; it < 4; it++)
#pragma unroll
            for (int ct = 0; ct < 2; ct++)
                acc[it][ct] = __builtin_amdgcn_mfma_f32_16x16x32_bf16(af[it], bfr[ct], acc[it][ct], 0, 0, 0);
    }
#pragma unroll
    for (int it = 0; it < 4; it++) {
#pragma unroll
        for (int ct = 0; ct < 2; ct++) {
            int m = m0 + it * 16 + q * 4;
            int n = n0 + wn + ct * 16 + l15;
#pragma unroll
            for (int r = 0; r < 4; r++)
                out[(size_t)(m + r) * 512 + n] = acc[it][ct][r];
        }
    }
}

// ---------------- K4: LayerNorm in place ----------------
__global__ __launch_bounds__(256) void k4_ln(float* __restrict__ out,
                                             const float* __restrict__ gamma,
                                             const float* __restrict__ beta)
{
    __shared__ float red[8];
    const int row = blockIdx.x, tid = threadIdx.x;
    float2 x = *reinterpret_cast<const float2*>(&out[(size_t)row * 512 + tid * 2]);
    float s = x.x + x.y;
    float ss = x.x * x.x + x.y * x.y;
#pragma unroll
    for (int off = 32; off > 0; off >>= 1) {
        s += __shfl_down(s, off);
        ss += __shfl_down(ss, off);
    }
    int wid = tid >> 6;
    if ((tid & 63) == 0) { red[wid * 2] = s; red[wid * 2 + 1] = ss; }
    __syncthreads();
    s = red[0] + red[2] + red[4] + red[6];
    ss = red[1] + red[3] + red[5] + red[7];
    float mean = s * (1.f / 512.f);
    float var = ss * (1.f / 512.f) - mean * mean;
    float inv = rsqrtf(var + 1e-5f);
    float g0 = gamma[tid * 2], g1 = gamma[tid * 2 + 1];
    float b0 = beta[tid * 2], b1 = beta[tid * 2 + 1];
    float2 o;
    o.x = (x.x - mean) * inv * g0 + b0;
    o.y = (x.y - mean) * inv * g1 + b1;
    *reinterpret_cast<float2*>(&out[(size_t)row * 512 + tid * 2]) = o;
}

extern "C" void kernel_launch(void* const* d_in, const int* in_sizes, int n_in,
                              void* d_out, int out_size, void* d_ws, size_t ws_size,
                              hipStream_t stream)
{
    const float* charge   = (const float*)d_in[0];
    const float* position = (const float*)d_in[1];
    const float* mass     = (const float*)d_in[2];
    const float* logbw    = (const float*)d_in[3];
    const float* Wc       = (const float*)d_in[4];
    const float* Wcb      = (const float*)d_in[5];
    const float* gamma    = (const float*)d_in[6];
    const float* beta     = (const float*)d_in[7];

    // ws layout: [0,32MB) projm_t (later aliased by wcb16) | [32,64MB) field (earlier aliased by ch16+wc16)
    unsigned short* projm_t = (unsigned short*)d_ws;
    unsigned short* field   = projm_t + (size_t)2048 * 8192;
    unsigned short* wcb16   = projm_t;                         // written after K2 (projm_t dead)
    unsigned short* ch16    = field;                           // dead before K2 writes field
    unsigned short* wc16    = field + (size_t)8192 * 512;
    // d_out as scratch for pos-derived arrays (dead before K3 writes out)
    unsigned short* posA  = (unsigned short*)d_out;            // 8192*32
    unsigned short* posB1 = posA + (size_t)8192 * 32;
    unsigned short* posB2 = posB1 + (size_t)8192 * 32;
    float* rsq = (float*)(posB2 + (size_t)8192 * 32);          // 8192 floats
    float* out = (float*)d_out;

    k0_pos<<<32, 256, 0, stream>>>(position, posA, posB1, posB2, rsq);
    k0_cvt<<<4096, 256, 0, stream>>>(charge, ch16);            // 8192*512
    k0_cvt<<<1024, 256, 0, stream>>>(Wc, wc16);                // 2048*512
    k1_proj<<<dim3(64, 16), 256, 0, stream>>>(wc16, ch16, mass, projm_t);
    k2_field<<<512, 256, 0, stream>>>(posA, posB1, posB2, rsq, logbw, projm_t, field);
    k0_cvt<<<1024, 256, 0, stream>>>(Wcb, wcb16);              // 512*2048
    k3_combine<<<dim3(4, 128), 256, 0, stream>>>(field, wcb16, out);
    k4_ln<<<8192, 256, 0, stream>>>(out, gamma, beta);
}